// Round 17
// baseline (348.189 us; speedup 1.0000x reference)
//
#include <hip/hip_runtime.h>
#include <math.h>

#define D 128

typedef __attribute__((ext_vector_type(8))) short bf16x8;
typedef __attribute__((ext_vector_type(4))) float f32x4;
typedef __attribute__((ext_vector_type(2))) float f32x2;

__device__ __forceinline__ float sigmoidf_(float x) { return 1.f / (1.f + __expf(-x)); }
__device__ __forceinline__ float u2f_lo(unsigned u) { return __uint_as_float(u << 16); }
__device__ __forceinline__ float u2f_hi(unsigned u) { return __uint_as_float(u & 0xffff0000u); }
__device__ __forceinline__ unsigned short f2b(float f) {
  unsigned u = __float_as_uint(f);
  return (unsigned short)((u + 0x7fffu + ((u >> 16) & 1u)) >> 16);  // RNE
}
__device__ __forceinline__ float leaky_(float v) { return v > 0.f ? v : 0.2f * v; }

// ---------- packing helpers ----------
__device__ __forceinline__ void pack_post_elem(const float* __restrict__ W,
                                               unsigned short* __restrict__ Bp, int i, float scale) {
  int j = i & 7;
  int lane = (i >> 3) & 63;
  int rest = i >> 9;
  int db = rest & 7;
  int kb = rest >> 3;
  int k = kb * 32 + ((lane >> 4) << 3) + j;
  int d = db * 16 + (lane & 15);
  int h = k >> 7, kk = k & 127;
  Bp[i] = f2b(W[((size_t)h * 128 + kk) * 128 + d] * scale);
}
__device__ __forceinline__ void pack_gru_elem(const float* __restrict__ S,
                                              unsigned short* __restrict__ Bp, int i) {
  int j = i & 7;
  int lane = (i >> 3) & 63;
  int rest = i >> 9;
  int db = rest % 24;
  int kb = rest / 24;
  int k = kb * 32 + ((lane >> 4) << 3) + j;
  int col = db * 16 + (lane & 15);
  Bp[i] = f2b(S[(size_t)col * 128 + k]);
}

// ---------- mega prep ----------
__global__ void __launch_bounds__(256) k_prep(const float* __restrict__ h0, unsigned short* __restrict__ h0b,
                                              const float* __restrict__ W1, const float* __restrict__ W2,
                                              const float* __restrict__ W3, const float* __restrict__ W4,
                                              const float* __restrict__ Wih, const float* __restrict__ Whh,
                                              unsigned short* __restrict__ B1, unsigned short* __restrict__ B2,
                                              unsigned short* __restrict__ B3, unsigned short* __restrict__ B4,
                                              unsigned short* __restrict__ Bih, unsigned short* __restrict__ Bhh,
                                              const float* __restrict__ as1, const float* __restrict__ ad1,
                                              const float* __restrict__ as2, const float* __restrict__ ad2,
                                              const float* __restrict__ as3, const float* __restrict__ ad3,
                                              const float* __restrict__ as4, const float* __restrict__ ad4,
                                              unsigned short* __restrict__ Pp1, float* __restrict__ Pf2,
                                              float* __restrict__ Pf3, float* __restrict__ Pf4,
                                              const int* __restrict__ dst, int* __restrict__ deg,
                                              int N, int E) {
  int i = blockIdx.x * 256 + threadIdx.x;
  const int NH = N * 128;
  if (i < NH) {
    h0b[i] = f2b(h0[i]);
    return;
  }
  i -= NH;
  if (i < 311296) {
    if (i < 65536) pack_post_elem(W1, B1, i, 0.25f);
    else if (i < 131072) pack_post_elem(W2, B2, i - 65536, 0.25f);
    else if (i < 196608) pack_post_elem(W3, B3, i - 131072, 0.25f);
    else if (i < 212992) pack_post_elem(W4, B4, i - 196608, 1.0f);
    else if (i < 262144) pack_gru_elem(Wih, Bih, i - 212992);
    else pack_gru_elem(Whh, Bhh, i - 262144);
    return;
  }
  i -= 311296;
  if (i < 2048) {
    int j = i & 7;
    int lane = (i >> 3) & 63;
    int kb = i >> 9;
    int k = kb * 32 + ((lane >> 4) << 3) + j;
    int col = lane & 15;
    float val = 0.f;
    if (col < 8) {
      int c = col >= 4;
      int h = c ? (col - 4) : col;
      const float* wrow = W1 + ((size_t)h * 128 + k) * 128;
      const float* av = (c ? ad1 : as1) + (size_t)h * 128;
      for (int d2 = 0; d2 < 128; ++d2) val += wrow[d2] * av[d2];
    }
    Pp1[i] = f2b(val);
    return;
  }
  i -= 2048;
  if (i < 3072) {
    int layer = i >> 10;
    int qq = i & 1023;
    int k = qq >> 3;
    int slot = qq & 7;
    const float *W, *as_, *ad_;
    float* out;
    int H;
    if (layer == 0) { W = W2; as_ = as2; ad_ = ad2; out = Pf2; H = 4; }
    else if (layer == 1) { W = W3; as_ = as3; ad_ = ad3; out = Pf3; H = 4; }
    else { W = W4; as_ = as4; ad_ = ad4; out = Pf4; H = 1; }
    int h = slot & 3;
    bool isEd = slot >= 4;
    float val = 0.f;
    if (h < H) {
      const float* wrow = W + ((size_t)h * 128 + k) * 128;
      const float* av = (isEd ? ad_ : as_) + (size_t)h * 128;
      for (int d2 = 0; d2 < 128; ++d2) val += wrow[d2] * av[d2];
    }
    out[qq] = val;
    return;
  }
  i -= 3072;
  if (i < E) atomicAdd(&deg[dst[i]], 1);
}

// ---------- CSR scan ----------
__global__ void __launch_bounds__(1024) k_scan(const int* __restrict__ deg, int* __restrict__ rowptr,
                                               int* __restrict__ fill, int N) {
  __shared__ int part[1024];
  const int tid = threadIdx.x;
  const int chunk = (N + 1023) / 1024;
  const int b = tid * chunk;
  const int e = min(N, b + chunk);
  int s = 0;
  for (int i = b; i < e; ++i) s += deg[i];
  part[tid] = s;
  __syncthreads();
  for (int off = 1; off < 1024; off <<= 1) {
    int v = (tid >= off) ? part[tid - off] : 0;
    __syncthreads();
    part[tid] += v;
    __syncthreads();
  }
  int run = (tid == 0) ? 0 : part[tid - 1];
  for (int i = b; i < e; ++i) {
    rowptr[i] = run;
    fill[i] = run;
    run += deg[i];
  }
  if (b < N && e == N) rowptr[N] = run;
}

// ---------- merged: CSR scatter + layer-1 es/ed MFMA ----------
__global__ void __launch_bounds__(256) k_scatter_esed(const int* __restrict__ src, const int* __restrict__ dst,
                                                      int* __restrict__ fill, int* __restrict__ srcs, int E,
                                                      const unsigned short* __restrict__ hb,
                                                      const unsigned short* __restrict__ Pp,
                                                      float* __restrict__ es, float* __restrict__ ed,
                                                      int N, int nS) {
  if ((int)blockIdx.x < nS) {
    int e = blockIdx.x * 256 + threadIdx.x;
    if (e < E) {
      int pos = atomicAdd(&fill[dst[e]], 1);
      srcs[pos] = src[e];
    }
    return;
  }
  const int blk = blockIdx.x - nS;
  const int w = threadIdx.x >> 6;
  const int lane = threadIdx.x & 63;
  const int r = lane & 15, g = lane >> 4;
  const int n0 = blk * 64 + w * 16;
  f32x4 acc = (f32x4)0.f;
  const int koff = g << 3;
#pragma unroll
  for (int kb = 0; kb < 4; ++kb) {
    int row = min(n0 + r, N - 1);
    bf16x8 a = *(const bf16x8*)&hb[(size_t)row * 128 + kb * 32 + koff];
    bf16x8 b = *(const bf16x8*)&Pp[((size_t)(kb * 64) + lane) * 8];
    acc = __builtin_amdgcn_mfma_f32_16x16x32_bf16(a, b, acc, 0, 0, 0);
  }
  const int rbase = n0 + g * 4;
#pragma unroll
  for (int i = 0; i < 4; ++i) {
    int row = rbase + i;
    if (row < N) {
      if (r < 4) es[(size_t)row * 4 + r] = acc[i];
      else if (r < 8) ed[(size_t)row * 4 + (r - 4)] = acc[i];
    }
  }
}

// ---------- fused layer kernel: 8 nodes / 256 threads (4 waves) ----------
// MODE: 0 = L1 (elu out + proj), 1 = GRU + proj, 2 = GRU + head. N must be multiple of 8.
template <int H, int MODE>
__global__ void __launch_bounds__(256) k_layer(const int* __restrict__ rowptr,
                                               const int* __restrict__ srcs,
                                               const float* __restrict__ es,
                                               const float* __restrict__ ed,
                                               const unsigned short* __restrict__ hbG,
                                               const unsigned short* __restrict__ Bp,
                                               const float* __restrict__ hf,
                                               const unsigned short* __restrict__ Bih,
                                               const unsigned short* __restrict__ Bhh,
                                               const float* __restrict__ bih,
                                               const float* __restrict__ bhh,
                                               float* __restrict__ houtf,
                                               unsigned short* __restrict__ houtb,
                                               const float* __restrict__ Pf,
                                               float* __restrict__ eso, float* __restrict__ edo, int Hn,
                                               const float* __restrict__ W5,
                                               const float* __restrict__ b5,
                                               float* __restrict__ out) {
  constexpr int KD = H * 128;
  __shared__ unsigned short ts[8][KD + 8];
  __shared__ unsigned short xs[16][136];
  __shared__ float s_pr[8][8][4];
  __shared__ __align__(16) unsigned s_off[8][32];
  __shared__ __align__(16) float s_af[8][32][H == 1 ? 1 : 4];

  const int tid = threadIdx.x;
  const int n0 = blockIdx.x * 8;

  // ======== phase 1: per-node gather (8 nodes x 32 lanes) ========
  {
    const int slot = tid >> 5;
    const int t = n0 + slot;
    const int l = tid & 31;
    const int q = l & 15;
    const int eg = l >> 4;
    const int b0 = rowptr[t];
    const int deg = rowptr[t + 1] - b0;
    if (deg == 0) {
      if (l < 16) {
#pragma unroll
        for (int h = 0; h < H; ++h)
          *(uint4*)&ts[slot][h * 128 + q * 8] = make_uint4(0u, 0u, 0u, 0u);
      }
    } else {
      float edv[H];
#pragma unroll
      for (int h = 0; h < H; ++h) edv[h] = ed[(size_t)t * H + h];
      f32x2 acc[H][4];
#pragma unroll
      for (int h = 0; h < H; ++h)
#pragma unroll
        for (int j = 0; j < 4; ++j) acc[h][j] = (f32x2)0.f;
      const char* hbase = (const char*)hbG + q * 16;

      if (deg <= 32) {
        const bool act = l < deg;
        int s = 0;
        float vv[H];
        if (act) {
          s = srcs[b0 + l];
          if constexpr (H == 4) {
            float4 ev = *(const float4*)&es[(size_t)s * 4];
            vv[0] = leaky_(ev.x + edv[0]);
            vv[1] = leaky_(ev.y + edv[1]);
            vv[2] = leaky_(ev.z + edv[2]);
            vv[3] = leaky_(ev.w + edv[3]);
          } else {
            vv[0] = leaky_(es[s] + edv[0]);
          }
        } else {
#pragma unroll
          for (int h = 0; h < H; ++h) vv[h] = -1e30f;
        }
        float mv[H];
#pragma unroll
        for (int h = 0; h < H; ++h) mv[h] = vv[h];
#pragma unroll
        for (int off = 16; off; off >>= 1)
#pragma unroll
          for (int h = 0; h < H; ++h) mv[h] = fmaxf(mv[h], __shfl_xor(mv[h], off));
        float e[H], den[H];
#pragma unroll
        for (int h = 0; h < H; ++h) {
          e[h] = act ? __expf(vv[h] - mv[h]) : 0.f;
          den[h] = e[h];
        }
#pragma unroll
        for (int off = 16; off; off >>= 1)
#pragma unroll
          for (int h = 0; h < H; ++h) den[h] += __shfl_xor(den[h], off);
        s_off[slot][l] = act ? ((unsigned)s << 8) : 0u;
#pragma unroll
        for (int h = 0; h < H; ++h) s_af[slot][l][h] = e[h] * (1.f / den[h]);
        const int steps = (deg + 1) >> 1;
#pragma unroll 4
        for (int e2 = 0; e2 < steps; ++e2) {
          const int ei = e2 * 2 + eg;
          unsigned off = s_off[slot][ei];
          float af[H];
          if constexpr (H == 4) {
            float4 a4 = *(const float4*)&s_af[slot][ei][0];
            af[0] = a4.x; af[1] = a4.y; af[2] = a4.z; af[3] = a4.w;
          } else {
            af[0] = s_af[slot][ei][0];
          }
          uint4 v = *(const uint4*)(hbase + off);
          f32x2 vf0 = {u2f_lo(v.x), u2f_hi(v.x)};
          f32x2 vf1 = {u2f_lo(v.y), u2f_hi(v.y)};
          f32x2 vf2 = {u2f_lo(v.z), u2f_hi(v.z)};
          f32x2 vf3 = {u2f_lo(v.w), u2f_hi(v.w)};
#pragma unroll
          for (int h = 0; h < H; ++h) {
            f32x2 a2 = {af[h], af[h]};
            acc[h][0] += a2 * vf0;
            acc[h][1] += a2 * vf1;
            acc[h][2] += a2 * vf2;
            acc[h][3] += a2 * vf3;
          }
        }
      } else {
        // slow path (deg > 32)
        float m[H], den[H], vreg[H];
        int sreg = 0;
#pragma unroll
        for (int h = 0; h < H; ++h) {
          m[h] = -1e30f;
          den[h] = 0.f;
          vreg[h] = -1e30f;
        }
        for (int i = l; i < deg; i += 32) {
          int s = srcs[b0 + i];
          float vv[H];
          if constexpr (H == 4) {
            float4 ev = *(const float4*)&es[(size_t)s * 4];
            vv[0] = ev.x + edv[0];
            vv[1] = ev.y + edv[1];
            vv[2] = ev.z + edv[2];
            vv[3] = ev.w + edv[3];
          } else {
            vv[0] = es[s] + edv[0];
          }
#pragma unroll
          for (int h = 0; h < H; ++h) {
            float v = leaky_(vv[h]);
            vv[h] = v;
            float nm = fmaxf(m[h], v);
            den[h] = den[h] * __expf(m[h] - nm) + __expf(v - nm);
            m[h] = nm;
          }
          if (i == l) {
            sreg = s;
#pragma unroll
            for (int h = 0; h < H; ++h) vreg[h] = vv[h];
          }
        }
#pragma unroll
        for (int off = 16; off; off >>= 1) {
#pragma unroll
          for (int h = 0; h < H; ++h) {
            float om = __shfl_xor(m[h], off);
            float od = __shfl_xor(den[h], off);
            float nm = fmaxf(m[h], om);
            den[h] = den[h] * __expf(m[h] - nm) + od * __expf(om - nm);
            m[h] = nm;
          }
        }
        float rden[H];
#pragma unroll
        for (int h = 0; h < H; ++h) rden[h] = 1.f / den[h];
        for (int c0 = 0; c0 < deg; c0 += 32) {
          const int ce = min(32, deg - c0);
          if (c0 == 0) {
            bool ok = l < deg;
            s_off[slot][l] = ok ? ((unsigned)sreg << 8) : 0u;
#pragma unroll
            for (int h = 0; h < H; ++h)
              s_af[slot][l][h] = ok ? (__expf(vreg[h] - m[h]) * rden[h]) : 0.f;
          } else {
            int i = c0 + l;
            bool ok = i < deg;
            int s = ok ? srcs[b0 + i] : 0;
            s_off[slot][l] = ok ? ((unsigned)s << 8) : 0u;
            float af[H];
#pragma unroll
            for (int h = 0; h < H; ++h) af[h] = 0.f;
            if (ok) {
              float vv[H];
              if constexpr (H == 4) {
                float4 ev = *(const float4*)&es[(size_t)s * 4];
                vv[0] = ev.x + edv[0];
                vv[1] = ev.y + edv[1];
                vv[2] = ev.z + edv[2];
                vv[3] = ev.w + edv[3];
              } else {
                vv[0] = es[s] + edv[0];
              }
#pragma unroll
              for (int h = 0; h < H; ++h)
                af[h] = __expf(leaky_(vv[h]) - m[h]) * rden[h];
            }
#pragma unroll
            for (int h = 0; h < H; ++h) s_af[slot][l][h] = af[h];
          }
          const int steps = (ce + 1) >> 1;
#pragma unroll 4
          for (int e2 = 0; e2 < steps; ++e2) {
            const int ei = e2 * 2 + eg;
            unsigned off = s_off[slot][ei];
            float af[H];
            if constexpr (H == 4) {
              float4 a4 = *(const float4*)&s_af[slot][ei][0];
              af[0] = a4.x; af[1] = a4.y; af[2] = a4.z; af[3] = a4.w;
            } else {
              af[0] = s_af[slot][ei][0];
            }
            uint4 v = *(const uint4*)(hbase + off);
            f32x2 vf0 = {u2f_lo(v.x), u2f_hi(v.x)};
            f32x2 vf1 = {u2f_lo(v.y), u2f_hi(v.y)};
            f32x2 vf2 = {u2f_lo(v.z), u2f_hi(v.z)};
            f32x2 vf3 = {u2f_lo(v.w), u2f_hi(v.w)};
#pragma unroll
            for (int h = 0; h < H; ++h) {
              f32x2 a2 = {af[h], af[h]};
              acc[h][0] += a2 * vf0;
              acc[h][1] += a2 * vf1;
              acc[h][2] += a2 * vf2;
              acc[h][3] += a2 * vf3;
            }
          }
        }
      }
#pragma unroll
      for (int h = 0; h < H; ++h)
#pragma unroll
        for (int j = 0; j < 4; ++j) {
          acc[h][j].x += __shfl_xor(acc[h][j].x, 16);
          acc[h][j].y += __shfl_xor(acc[h][j].y, 16);
        }
      if (l < 16) {
#pragma unroll
        for (int h = 0; h < H; ++h) {
          uint4 pk;
          pk.x = (unsigned)f2b(acc[h][0].x) | ((unsigned)f2b(acc[h][0].y) << 16);
          pk.y = (unsigned)f2b(acc[h][1].x) | ((unsigned)f2b(acc[h][1].y) << 16);
          pk.z = (unsigned)f2b(acc[h][2].x) | ((unsigned)f2b(acc[h][2].y) << 16);
          pk.w = (unsigned)f2b(acc[h][3].x) | ((unsigned)f2b(acc[h][3].y) << 16);
          *(uint4*)&ts[slot][h * 128 + q * 8] = pk;
        }
      }
    }
  }
  __syncthreads();

  // ======== phase 2: post GEMM (4 waves, wave w -> col tiles {2w, 2w+1}) ========
  // MFMA uses 16 A-rows; rows 8-15 mirror rows 0-7 (ts read r&7), results discarded.
  const int w = tid >> 6;
  const int lane = tid & 63;
  const int r = lane & 15, g = lane >> 4;
  const int koff = g << 3;
  f32x4 pacc[2];
  pacc[0] = (f32x4)0.f;
  pacc[1] = (f32x4)0.f;
#pragma unroll
  for (int kb = 0; kb < KD / 32; ++kb) {
    bf16x8 a = *(const bf16x8*)&ts[r & 7][kb * 32 + koff];
#pragma unroll
    for (int t = 0; t < 2; ++t) {
      bf16x8 b = *(const bf16x8*)&Bp[((size_t)(kb * 8 + w * 2 + t) * 64 + lane) * 8];
      pacc[t] = __builtin_amdgcn_mfma_f32_16x16x32_bf16(a, b, pacc[t], 0, 0, 0);
    }
  }

  if constexpr (MODE == 0) {
    float ps[4][8];
#pragma unroll
    for (int i = 0; i < 4; ++i)
#pragma unroll
      for (int c = 0; c < 8; ++c) ps[i][c] = 0.f;
#pragma unroll
    for (int t = 0; t < 2; ++t) {
      const int col = (w * 2 + t) * 16 + r;
      float4 pj0 = *(const float4*)&Pf[col * 8];
      float4 pj1 = *(const float4*)&Pf[col * 8 + 4];
#pragma unroll
      for (int i = 0; i < 4; ++i) {
        const int row8 = g * 4 + i;
        float o = pacc[t][i];
        o = o > 0.f ? o : expm1f(o);
        if (row8 < 8) {
          const int row = n0 + row8;
          houtf[(size_t)row * 128 + col] = o;
          houtb[(size_t)row * 128 + col] = f2b(o);
        }
        ps[i][0] += o * pj0.x; ps[i][1] += o * pj0.y;
        ps[i][2] += o * pj0.z; ps[i][3] += o * pj0.w;
        ps[i][4] += o * pj1.x; ps[i][5] += o * pj1.y;
        ps[i][6] += o * pj1.z; ps[i][7] += o * pj1.w;
      }
    }
#pragma unroll
    for (int off = 1; off < 16; off <<= 1)
#pragma unroll
      for (int i = 0; i < 4; ++i)
#pragma unroll
        for (int c = 0; c < 8; ++c) ps[i][c] += __shfl_xor(ps[i][c], off);
    if (r == 0) {
#pragma unroll
      for (int i = 0; i < 4; ++i) {
        const int row8 = g * 4 + i;
        if (row8 < 8) {
#pragma unroll
          for (int c = 0; c < 8; ++c) s_pr[row8][c][w] = ps[i][c];
        }
      }
    }
    __syncthreads();
    if (tid < 64) {
      int row = tid >> 3;
      int c = tid & 7;
      float val = s_pr[row][c][0] + s_pr[row][c][1] + s_pr[row][c][2] + s_pr[row][c][3];
      int gr = n0 + row;
      if (c < 4) eso[(size_t)gr * 4 + c] = val;
      else edo[(size_t)gr * 4 + (c - 4)] = val;
    }
  } else {
#pragma unroll
    for (int t = 0; t < 2; ++t) {
      const int col = (w * 2 + t) * 16 + r;
#pragma unroll
      for (int i = 0; i < 4; ++i) {
        float o = pacc[t][i];
        o = o > 0.f ? o : expm1f(o);
        xs[g * 4 + i][col] = f2b(o);  // rows 8-15 hold mirrored values; discarded later
      }
    }
    __syncthreads();
    f32x4 ai[3][2], ah[3][2];
#pragma unroll
    for (int p = 0; p < 3; ++p)
#pragma unroll
      for (int t = 0; t < 2; ++t) {
        ai[p][t] = (f32x4)0.f;
        ah[p][t] = (f32x4)0.f;
      }
    const int rowA = n0 + (r & 7);  // rows 8-15 mirror 0-7
#pragma unroll
    for (int kb = 0; kb < 4; ++kb) {
      bf16x8 ax = *(const bf16x8*)&xs[r][kb * 32 + koff];
      bf16x8 ahr = *(const bf16x8*)&hbG[(size_t)rowA * 128 + kb * 32 + koff];
#pragma unroll
      for (int p = 0; p < 3; ++p) {
#pragma unroll
        for (int t = 0; t < 2; ++t) {
          const int ct = p * 8 + w * 2 + t;
          bf16x8 bi = *(const bf16x8*)&Bih[((size_t)(kb * 24 + ct) * 64 + lane) * 8];
          bf16x8 bh = *(const bf16x8*)&Bhh[((size_t)(kb * 24 + ct) * 64 + lane) * 8];
          ai[p][t] = __builtin_amdgcn_mfma_f32_16x16x32_bf16(ax, bi, ai[p][t], 0, 0, 0);
          ah[p][t] = __builtin_amdgcn_mfma_f32_16x16x32_bf16(ahr, bh, ah[p][t], 0, 0, 0);
        }
      }
    }
    if constexpr (MODE == 1) {
      float ps[4][8];
#pragma unroll
      for (int i = 0; i < 4; ++i)
#pragma unroll
        for (int c = 0; c < 8; ++c) ps[i][c] = 0.f;
#pragma unroll
      for (int t = 0; t < 2; ++t) {
        const int j = (w * 2 + t) * 16 + r;
        const float bir = bih[j], biz = bih[128 + j], bin = bih[256 + j];
        const float bhr = bhh[j], bhz = bhh[128 + j], bhn = bhh[256 + j];
        float4 pj0 = *(const float4*)&Pf[j * 8];
        float4 pj1 = *(const float4*)&Pf[j * 8 + 4];
#pragma unroll
        for (int i = 0; i < 4; ++i) {
          const int row8 = g * 4 + i;
          const int row = n0 + (row8 & 7);
          float rr = sigmoidf_(ai[0][t][i] + bir + ah[0][t][i] + bhr);
          float z = sigmoidf_(ai[1][t][i] + biz + ah[1][t][i] + bhz);
          float nn = tanhf(ai[2][t][i] + bin + rr * (ah[2][t][i] + bhn));
          float hp = hf[(size_t)row * 128 + j];
          float o = (1.f - z) * nn + z * hp;
          if (row8 < 8) {
            houtf[(size_t)row * 128 + j] = o;
            houtb[(size_t)row * 128 + j] = f2b(o);
          }
          ps[i][0] += o * pj0.x; ps[i][1] += o * pj0.y;
          ps[i][2] += o * pj0.z; ps[i][3] += o * pj0.w;
          ps[i][4] += o * pj1.x; ps[i][5] += o * pj1.y;
          ps[i][6] += o * pj1.z; ps[i][7] += o * pj1.w;
        }
      }
#pragma unroll
      for (int off = 1; off < 16; off <<= 1)
#pragma unroll
        for (int i = 0; i < 4; ++i)
#pragma unroll
          for (int c = 0; c < 8; ++c) ps[i][c] += __shfl_xor(ps[i][c], off);
      if (r == 0) {
#pragma unroll
        for (int i = 0; i < 4; ++i) {
          const int row8 = g * 4 + i;
          if (row8 < 8) {
#pragma unroll
            for (int c = 0; c < 8; ++c) s_pr[row8][c][w] = ps[i][c];
          }
        }
      }
      __syncthreads();
      if (tid < 64) {
        int row = tid >> 3;
        int c = tid & 7;
        float val = s_pr[row][c][0] + s_pr[row][c][1] + s_pr[row][c][2] + s_pr[row][c][3];
        int gr = n0 + row;
        if (c < Hn) eso[(size_t)gr * Hn + c] = val;
        else if (c >= 4 && c < 4 + Hn) edo[(size_t)gr * Hn + (c - 4)] = val;
      }
    } else {
      // MODE == 2: fused sigmoid(h@W5 + b5) head
      float pfin[4] = {0.f, 0.f, 0.f, 0.f};
#pragma unroll
      for (int t = 0; t < 2; ++t) {
        const int j = (w * 2 + t) * 16 + r;
        const float bir = bih[j], biz = bih[128 + j], bin = bih[256 + j];
        const float bhr = bhh[j], bhz = bhh[128 + j], bhn = bhh[256 + j];
        const float w5 = W5[j];
#pragma unroll
        for (int i = 0; i < 4; ++i) {
          const int row8 = g * 4 + i;
          const int row = n0 + (row8 & 7);
          float rr = sigmoidf_(ai[0][t][i] + bir + ah[0][t][i] + bhr);
          float z = sigmoidf_(ai[1][t][i] + biz + ah[1][t][i] + bhz);
          float nn = tanhf(ai[2][t][i] + bin + rr * (ah[2][t][i] + bhn));
          float hp = hf[(size_t)row * 128 + j];
          float o = (1.f - z) * nn + z * hp;
          pfin[i] += o * w5;
        }
      }
#pragma unroll
      for (int off = 1; off < 16; off <<= 1)
#pragma unroll
        for (int i = 0; i < 4; ++i) pfin[i] += __shfl_xor(pfin[i], off);
      if (r == 0) {
#pragma unroll
        for (int i = 0; i < 4; ++i) {
          const int row8 = g * 4 + i;
          if (row8 < 8) s_pr[row8][0][w] = pfin[i];
        }
      }
      __syncthreads();
      if (tid < 8) {
        float s = s_pr[tid][0][0] + s_pr[tid][0][1] +
                  s_pr[tid][0][2] + s_pr[tid][0][3] + b5[0];
        out[n0 + tid] = sigmoidf_(s);
      }
    }
  }
}

extern "C" void kernel_launch(void* const* d_in, const int* in_sizes, int n_in,
                              void* d_out, int out_size, void* d_ws, size_t ws_size,
                              hipStream_t stream) {
  const float* h0 = (const float*)d_in[0];
  const int* ei = (const int*)d_in[1];
  const float* W1 = (const float*)d_in[2];
  const float* as1 = (const float*)d_in[3];
  const float* ad1 = (const float*)d_in[4];
  const float* W2 = (const float*)d_in[5];
  const float* as2 = (const float*)d_in[6];
  const float* ad2 = (const float*)d_in[7];
  const float* W3 = (const float*)d_in[8];
  const float* as3 = (const float*)d_in[9];
  const float* ad3 = (const float*)d_in[10];
  const float* W4 = (const float*)d_in[11];
  const float* as4 = (const float*)d_in[12];
  const float* ad4 = (const float*)d_in[13];
  const float* Wih = (const float*)d_in[14];
  const float* Whh = (const float*)d_in[15];
  const float* bih = (const float*)d_in[16];
  const float* bhh = (const float*)d_in[17];
  const float* W5 = (const float*)d_in[18];
  const float* b5 = (const float*)d_in[19];

  const int N = in_sizes[0] / D;  // 20000
  const int E = in_sizes[1] / 2;  // 320000
  const int* src = ei;
  const int* dst = ei + E;

  // ---- workspace layout ----
  float* ws = (float*)d_ws;
  float* hA = ws;                                     // N*128 f32
  float* hB = hA + (size_t)N * 128;                   // N*128 f32
  float* esA = hB + (size_t)N * 128;                  // N*4
  float* edA = esA + (size_t)N * 4;                   // N*4
  float* esB = edA + (size_t)N * 4;                   // N*4
  float* edB = esB + (size_t)N * 4;                   // N*4
  unsigned short* h0b = (unsigned short*)(edB + (size_t)N * 4);  // N*128 us
  unsigned short* hAb = h0b + (size_t)N * 128;        // N*128 us
  unsigned short* hBb = hAb + (size_t)N * 128;        // N*128 us
  unsigned short* B1 = hBb + (size_t)N * 128;         // 65536 us
  unsigned short* B2 = B1 + 65536;                    // 65536 us
  unsigned short* B3 = B2 + 65536;                    // 65536 us
  unsigned short* B4 = B3 + 65536;                    // 16384 us
  unsigned short* Bih = B4 + 16384;                   // 49152 us
  unsigned short* Bhh = Bih + 49152;                  // 49152 us
  unsigned short* Pp1 = Bhh + 49152;                  // 2048 us
  float* Pf2 = (float*)(Pp1 + 2048);                  // 1024 f
  float* Pf3 = Pf2 + 1024;                            // 1024 f
  float* Pf4 = Pf3 + 1024;                            // 1024 f
  int* deg = (int*)(Pf4 + 1024);                      // N
  int* rowptr = deg + N;                              // N+1
  int* fill = rowptr + N + 1;                         // N
  int* srcs = fill + N;                               // E

  // ---- prep ----
  hipMemsetAsync(deg, 0, (size_t)N * 4, stream);
  {
    const int total = N * 128 + 311296 + 2048 + 3072 + E;
    k_prep<<<(total + 255) / 256, 256, 0, stream>>>(
        h0, h0b, W1, W2, W3, W4, Wih, Whh, B1, B2, B3, B4, Bih, Bhh,
        as1, ad1, as2, ad2, as3, ad3, as4, ad4, Pp1, Pf2, Pf3, Pf4, dst, deg, N, E);
  }
  k_scan<<<1, 1024, 0, stream>>>(deg, rowptr, fill, N);
  {
    const int nS = (E + 255) / 256;
    const int nE = (N + 63) / 64;
    k_scatter_esed<<<nS + nE, 256, 0, stream>>>(src, dst, fill, srcs, E,
                                                h0b, Pp1, esA, edA, N, nS);
  }

  const int gL = N / 8;  // 2500

  // ---- layer 1: H=4, no GRU; emits h1 (hA/hAb) + es/ed(L2) -> B buffers ----
  k_layer<4, 0><<<gL, 256, 0, stream>>>(rowptr, srcs, esA, edA, h0b, B1,
                                        nullptr, nullptr, nullptr, nullptr, nullptr,
                                        hA, hAb, Pf2, esB, edB, 4, nullptr, nullptr, nullptr);
  // ---- layer 2: H=4, GRU; emits h2 (hB/hBb) + es/ed(L3) -> A buffers ----
  k_layer<4, 1><<<gL, 256, 0, stream>>>(rowptr, srcs, esB, edB, hAb, B2,
                                        hA, Bih, Bhh, bih, bhh,
                                        hB, hBb, Pf3, esA, edA, 4, nullptr, nullptr, nullptr);
  // ---- layer 3: H=4, GRU; emits h3 (hA/hAb) + es/ed(L4, Hn=1) -> B buffers ----
  k_layer<4, 1><<<gL, 256, 0, stream>>>(rowptr, srcs, esA, edA, hBb, B3,
                                        hB, Bih, Bhh, bih, bhh,
                                        hA, hAb, Pf4, esB, edB, 1, nullptr, nullptr, nullptr);
  // ---- layer 4: H=1, GRU + fused output head ----
  k_layer<1, 2><<<gL, 256, 0, stream>>>(rowptr, srcs, esB, edB, hAb, B4,
                                        hA, Bih, Bhh, bih, bhh,
                                        nullptr, nullptr, nullptr, nullptr, nullptr, 0,
                                        W5, b5, (float*)d_out);
}

// Round 18
// 262.609 us; speedup vs baseline: 1.3259x; 1.3259x over previous
//
#include <hip/hip_runtime.h>
#include <math.h>

#define D 128

typedef __attribute__((ext_vector_type(8))) short bf16x8;
typedef __attribute__((ext_vector_type(4))) float f32x4;
typedef __attribute__((ext_vector_type(2))) float f32x2;

__device__ __forceinline__ float sigmoidf_(float x) { return 1.f / (1.f + __expf(-x)); }
__device__ __forceinline__ float u2f_lo(unsigned u) { return __uint_as_float(u << 16); }
__device__ __forceinline__ float u2f_hi(unsigned u) { return __uint_as_float(u & 0xffff0000u); }
__device__ __forceinline__ unsigned short f2b(float f) {
  unsigned u = __float_as_uint(f);
  return (unsigned short)((u + 0x7fffu + ((u >> 16) & 1u)) >> 16);  // RNE
}
__device__ __forceinline__ float leaky_(float v) { return v > 0.f ? v : 0.2f * v; }

// ---------- packing helpers ----------
__device__ __forceinline__ void pack_post_elem(const float* __restrict__ W,
                                               unsigned short* __restrict__ Bp, int i, float scale) {
  int j = i & 7;
  int lane = (i >> 3) & 63;
  int rest = i >> 9;
  int db = rest & 7;
  int kb = rest >> 3;
  int k = kb * 32 + ((lane >> 4) << 3) + j;
  int d = db * 16 + (lane & 15);
  int h = k >> 7, kk = k & 127;
  Bp[i] = f2b(W[((size_t)h * 128 + kk) * 128 + d] * scale);
}
__device__ __forceinline__ void pack_gru_elem(const float* __restrict__ S,
                                              unsigned short* __restrict__ Bp, int i) {
  int j = i & 7;
  int lane = (i >> 3) & 63;
  int rest = i >> 9;
  int db = rest % 24;
  int kb = rest / 24;
  int k = kb * 32 + ((lane >> 4) << 3) + j;
  int col = db * 16 + (lane & 15);
  Bp[i] = f2b(S[(size_t)col * 128 + k]);
}

// ---------- mega prep: f2b(h0) + pack all weights + projections + degree histogram ----------
__global__ void __launch_bounds__(256) k_prep(const float* __restrict__ h0, unsigned short* __restrict__ h0b,
                                              const float* __restrict__ W1, const float* __restrict__ W2,
                                              const float* __restrict__ W3, const float* __restrict__ W4,
                                              const float* __restrict__ Wih, const float* __restrict__ Whh,
                                              unsigned short* __restrict__ B1, unsigned short* __restrict__ B2,
                                              unsigned short* __restrict__ B3, unsigned short* __restrict__ B4,
                                              unsigned short* __restrict__ Bih, unsigned short* __restrict__ Bhh,
                                              const float* __restrict__ as1, const float* __restrict__ ad1,
                                              const float* __restrict__ as2, const float* __restrict__ ad2,
                                              const float* __restrict__ as3, const float* __restrict__ ad3,
                                              const float* __restrict__ as4, const float* __restrict__ ad4,
                                              unsigned short* __restrict__ Pp1, float* __restrict__ Pf2,
                                              float* __restrict__ Pf3, float* __restrict__ Pf4,
                                              const int* __restrict__ dst, int* __restrict__ deg,
                                              int N, int E) {
  int i = blockIdx.x * 256 + threadIdx.x;
  const int NH = N * 128;
  if (i < NH) {
    h0b[i] = f2b(h0[i]);
    return;
  }
  i -= NH;
  if (i < 311296) {
    if (i < 65536) pack_post_elem(W1, B1, i, 0.25f);
    else if (i < 131072) pack_post_elem(W2, B2, i - 65536, 0.25f);
    else if (i < 196608) pack_post_elem(W3, B3, i - 131072, 0.25f);
    else if (i < 212992) pack_post_elem(W4, B4, i - 196608, 1.0f);
    else if (i < 262144) pack_gru_elem(Wih, Bih, i - 212992);
    else pack_gru_elem(Whh, Bhh, i - 262144);
    return;
  }
  i -= 311296;
  if (i < 2048) {
    int j = i & 7;
    int lane = (i >> 3) & 63;
    int kb = i >> 9;
    int k = kb * 32 + ((lane >> 4) << 3) + j;
    int col = lane & 15;
    float val = 0.f;
    if (col < 8) {
      int c = col >= 4;
      int h = c ? (col - 4) : col;
      const float* wrow = W1 + ((size_t)h * 128 + k) * 128;
      const float* av = (c ? ad1 : as1) + (size_t)h * 128;
      for (int d2 = 0; d2 < 128; ++d2) val += wrow[d2] * av[d2];
    }
    Pp1[i] = f2b(val);
    return;
  }
  i -= 2048;
  if (i < 3072) {
    int layer = i >> 10;
    int qq = i & 1023;
    int k = qq >> 3;
    int slot = qq & 7;
    const float *W, *as_, *ad_;
    float* out;
    int H;
    if (layer == 0) { W = W2; as_ = as2; ad_ = ad2; out = Pf2; H = 4; }
    else if (layer == 1) { W = W3; as_ = as3; ad_ = ad3; out = Pf3; H = 4; }
    else { W = W4; as_ = as4; ad_ = ad4; out = Pf4; H = 1; }
    int h = slot & 3;
    bool isEd = slot >= 4;
    float val = 0.f;
    if (h < H) {
      const float* wrow = W + ((size_t)h * 128 + k) * 128;
      const float* av = (isEd ? ad_ : as_) + (size_t)h * 128;
      for (int d2 = 0; d2 < 128; ++d2) val += wrow[d2] * av[d2];
    }
    out[qq] = val;
    return;
  }
  i -= 3072;
  if (i < E) atomicAdd(&deg[dst[i]], 1);
}

// ---------- CSR scan ----------
__global__ void __launch_bounds__(1024) k_scan(const int* __restrict__ deg, int* __restrict__ rowptr,
                                               int* __restrict__ fill, int N) {
  __shared__ int part[1024];
  const int tid = threadIdx.x;
  const int chunk = (N + 1023) / 1024;
  const int b = tid * chunk;
  const int e = min(N, b + chunk);
  int s = 0;
  for (int i = b; i < e; ++i) s += deg[i];
  part[tid] = s;
  __syncthreads();
  for (int off = 1; off < 1024; off <<= 1) {
    int v = (tid >= off) ? part[tid - off] : 0;
    __syncthreads();
    part[tid] += v;
    __syncthreads();
  }
  int run = (tid == 0) ? 0 : part[tid - 1];
  for (int i = b; i < e; ++i) {
    rowptr[i] = run;
    fill[i] = run;
    run += deg[i];
  }
  if (b < N && e == N) rowptr[N] = run;
}

// ---------- merged: CSR scatter (blocks [0,nS)) + layer-1 es/ed MFMA (blocks [nS,...)) ----------
__global__ void __launch_bounds__(256) k_scatter_esed(const int* __restrict__ src, const int* __restrict__ dst,
                                                      int* __restrict__ fill, int* __restrict__ srcs, int E,
                                                      const unsigned short* __restrict__ hb,
                                                      const unsigned short* __restrict__ Pp,
                                                      float* __restrict__ es, float* __restrict__ ed,
                                                      int N, int nS) {
  if ((int)blockIdx.x < nS) {
    int e = blockIdx.x * 256 + threadIdx.x;
    if (e < E) {
      int pos = atomicAdd(&fill[dst[e]], 1);
      srcs[pos] = src[e];
    }
    return;
  }
  const int blk = blockIdx.x - nS;
  const int w = threadIdx.x >> 6;
  const int lane = threadIdx.x & 63;
  const int r = lane & 15, g = lane >> 4;
  const int n0 = blk * 64 + w * 16;
  f32x4 acc = (f32x4)0.f;
  const int koff = g << 3;
#pragma unroll
  for (int kb = 0; kb < 4; ++kb) {
    int row = min(n0 + r, N - 1);
    bf16x8 a = *(const bf16x8*)&hb[(size_t)row * 128 + kb * 32 + koff];
    bf16x8 b = *(const bf16x8*)&Pp[((size_t)(kb * 64) + lane) * 8];
    acc = __builtin_amdgcn_mfma_f32_16x16x32_bf16(a, b, acc, 0, 0, 0);
  }
  const int rbase = n0 + g * 4;
#pragma unroll
  for (int i = 0; i < 4; ++i) {
    int row = rbase + i;
    if (row < N) {
      if (r < 4) es[(size_t)row * 4 + r] = acc[i];
      else if (r < 8) ed[(size_t)row * 4 + (r - 4)] = acc[i];
    }
  }
}

// ---------- fused layer kernel: gather(LDS) -> post GEMM -> {elu | GRU} -> {proj | head} ----------
// 512 threads, 16 nodes/block. H in {4,1}; MODE: 0 = L1 (no GRU, elu out f32+bf16 + proj),
// 1 = GRU + proj, 2 = GRU + sigmoid(h@W5+b5) head.
// NOTE: no early returns (block-wide barriers); N must be a multiple of 16.
template <int H, int MODE>
__global__ void __launch_bounds__(512) k_layer(const int* __restrict__ rowptr,
                                               const int* __restrict__ srcs,
                                               const float* __restrict__ es,
                                               const float* __restrict__ ed,
                                               const unsigned short* __restrict__ hbG,
                                               const unsigned short* __restrict__ Bp,
                                               const float* __restrict__ hf,
                                               const unsigned short* __restrict__ Bih,
                                               const unsigned short* __restrict__ Bhh,
                                               const float* __restrict__ bih,
                                               const float* __restrict__ bhh,
                                               float* __restrict__ houtf,
                                               unsigned short* __restrict__ houtb,
                                               const float* __restrict__ Pf,
                                               float* __restrict__ eso, float* __restrict__ edo, int Hn,
                                               const float* __restrict__ W5,
                                               const float* __restrict__ b5,
                                               float* __restrict__ out) {
  constexpr int KD = H * 128;
  __shared__ unsigned short ts[16][KD + 8];   // +8 pad: row stride 4 banks -> only free 2-way alias
  __shared__ unsigned short xs[16][136];
  __shared__ float s_pr[16][8][8];
  __shared__ __align__(16) unsigned s_off[16][32];
  __shared__ __align__(16) float s_af[16][32][H == 1 ? 1 : 4];

  const int tid = threadIdx.x;
  const int n0 = blockIdx.x * 16;

  // ======== phase 1: per-node gather (16 nodes x 32 lanes) ========
  {
    const int slot = tid >> 5;
    const int t = n0 + slot;
    const int l = tid & 31;
    const int q = l & 15;
    const int eg = l >> 4;
    const int b0 = rowptr[t];
    const int deg = rowptr[t + 1] - b0;
    if (deg == 0) {
      if (l < 16) {
#pragma unroll
        for (int h = 0; h < H; ++h)
          *(uint4*)&ts[slot][h * 128 + q * 8] = make_uint4(0u, 0u, 0u, 0u);
      }
    } else {
      float edv[H];
#pragma unroll
      for (int h = 0; h < H; ++h) edv[h] = ed[(size_t)t * H + h];
      f32x2 acc[H][4];
#pragma unroll
      for (int h = 0; h < H; ++h)
#pragma unroll
        for (int j = 0; j < 4; ++j) acc[h][j] = (f32x2)0.f;
      const char* hbase = (const char*)hbG + q * 16;

      if (deg <= 32) {
        const bool act = l < deg;
        int s = 0;
        float vv[H];
        if (act) {
          s = srcs[b0 + l];
          if constexpr (H == 4) {
            float4 ev = *(const float4*)&es[(size_t)s * 4];
            vv[0] = leaky_(ev.x + edv[0]);
            vv[1] = leaky_(ev.y + edv[1]);
            vv[2] = leaky_(ev.z + edv[2]);
            vv[3] = leaky_(ev.w + edv[3]);
          } else {
            vv[0] = leaky_(es[s] + edv[0]);
          }
        } else {
#pragma unroll
          for (int h = 0; h < H; ++h) vv[h] = -1e30f;
        }
        float mv[H];
#pragma unroll
        for (int h = 0; h < H; ++h) mv[h] = vv[h];
#pragma unroll
        for (int off = 16; off; off >>= 1)
#pragma unroll
          for (int h = 0; h < H; ++h) mv[h] = fmaxf(mv[h], __shfl_xor(mv[h], off));
        float e[H], den[H];
#pragma unroll
        for (int h = 0; h < H; ++h) {
          e[h] = act ? __expf(vv[h] - mv[h]) : 0.f;
          den[h] = e[h];
        }
#pragma unroll
        for (int off = 16; off; off >>= 1)
#pragma unroll
          for (int h = 0; h < H; ++h) den[h] += __shfl_xor(den[h], off);
        s_off[slot][l] = act ? ((unsigned)s << 8) : 0u;
#pragma unroll
        for (int h = 0; h < H; ++h) s_af[slot][l][h] = e[h] * (1.f / den[h]);
        const int steps = (deg + 1) >> 1;
#pragma unroll 4
        for (int e2 = 0; e2 < steps; ++e2) {
          const int ei = e2 * 2 + eg;
          unsigned off = s_off[slot][ei];
          float af[H];
          if constexpr (H == 4) {
            float4 a4 = *(const float4*)&s_af[slot][ei][0];
            af[0] = a4.x; af[1] = a4.y; af[2] = a4.z; af[3] = a4.w;
          } else {
            af[0] = s_af[slot][ei][0];
          }
          uint4 v = *(const uint4*)(hbase + off);
          f32x2 vf0 = {u2f_lo(v.x), u2f_hi(v.x)};
          f32x2 vf1 = {u2f_lo(v.y), u2f_hi(v.y)};
          f32x2 vf2 = {u2f_lo(v.z), u2f_hi(v.z)};
          f32x2 vf3 = {u2f_lo(v.w), u2f_hi(v.w)};
#pragma unroll
          for (int h = 0; h < H; ++h) {
            f32x2 a2 = {af[h], af[h]};
            acc[h][0] += a2 * vf0;
            acc[h][1] += a2 * vf1;
            acc[h][2] += a2 * vf2;
            acc[h][3] += a2 * vf3;
          }
        }
      } else {
        // slow path (deg > 32): online softmax + chunked staging
        float m[H], den[H], vreg[H];
        int sreg = 0;
#pragma unroll
        for (int h = 0; h < H; ++h) {
          m[h] = -1e30f;
          den[h] = 0.f;
          vreg[h] = -1e30f;
        }
        for (int i = l; i < deg; i += 32) {
          int s = srcs[b0 + i];
          float vv[H];
          if constexpr (H == 4) {
            float4 ev = *(const float4*)&es[(size_t)s * 4];
            vv[0] = ev.x + edv[0];
            vv[1] = ev.y + edv[1];
            vv[2] = ev.z + edv[2];
            vv[3] = ev.w + edv[3];
          } else {
            vv[0] = es[s] + edv[0];
          }
#pragma unroll
          for (int h = 0; h < H; ++h) {
            float v = leaky_(vv[h]);
            vv[h] = v;
            float nm = fmaxf(m[h], v);
            den[h] = den[h] * __expf(m[h] - nm) + __expf(v - nm);
            m[h] = nm;
          }
          if (i == l) {
            sreg = s;
#pragma unroll
            for (int h = 0; h < H; ++h) vreg[h] = vv[h];
          }
        }
#pragma unroll
        for (int off = 16; off; off >>= 1) {
#pragma unroll
          for (int h = 0; h < H; ++h) {
            float om = __shfl_xor(m[h], off);
            float od = __shfl_xor(den[h], off);
            float nm = fmaxf(m[h], om);
            den[h] = den[h] * __expf(m[h] - nm) + od * __expf(om - nm);
            m[h] = nm;
          }
        }
        float rden[H];
#pragma unroll
        for (int h = 0; h < H; ++h) rden[h] = 1.f / den[h];
        for (int c0 = 0; c0 < deg; c0 += 32) {
          const int ce = min(32, deg - c0);
          if (c0 == 0) {
            bool ok = l < deg;
            s_off[slot][l] = ok ? ((unsigned)sreg << 8) : 0u;
#pragma unroll
            for (int h = 0; h < H; ++h)
              s_af[slot][l][h] = ok ? (__expf(vreg[h] - m[h]) * rden[h]) : 0.f;
          } else {
            int i = c0 + l;
            bool ok = i < deg;
            int s = ok ? srcs[b0 + i] : 0;
            s_off[slot][l] = ok ? ((unsigned)s << 8) : 0u;
            float af[H];
#pragma unroll
            for (int h = 0; h < H; ++h) af[h] = 0.f;
            if (ok) {
              float vv[H];
              if constexpr (H == 4) {
                float4 ev = *(const float4*)&es[(size_t)s * 4];
                vv[0] = ev.x + edv[0];
                vv[1] = ev.y + edv[1];
                vv[2] = ev.z + edv[2];
                vv[3] = ev.w + edv[3];
              } else {
                vv[0] = es[s] + edv[0];
              }
#pragma unroll
              for (int h = 0; h < H; ++h)
                af[h] = __expf(leaky_(vv[h]) - m[h]) * rden[h];
            }
#pragma unroll
            for (int h = 0; h < H; ++h) s_af[slot][l][h] = af[h];
          }
          const int steps = (ce + 1) >> 1;
#pragma unroll 4
          for (int e2 = 0; e2 < steps; ++e2) {
            const int ei = e2 * 2 + eg;
            unsigned off = s_off[slot][ei];
            float af[H];
            if constexpr (H == 4) {
              float4 a4 = *(const float4*)&s_af[slot][ei][0];
              af[0] = a4.x; af[1] = a4.y; af[2] = a4.z; af[3] = a4.w;
            } else {
              af[0] = s_af[slot][ei][0];
            }
            uint4 v = *(const uint4*)(hbase + off);
            f32x2 vf0 = {u2f_lo(v.x), u2f_hi(v.x)};
            f32x2 vf1 = {u2f_lo(v.y), u2f_hi(v.y)};
            f32x2 vf2 = {u2f_lo(v.z), u2f_hi(v.z)};
            f32x2 vf3 = {u2f_lo(v.w), u2f_hi(v.w)};
#pragma unroll
            for (int h = 0; h < H; ++h) {
              f32x2 a2 = {af[h], af[h]};
              acc[h][0] += a2 * vf0;
              acc[h][1] += a2 * vf1;
              acc[h][2] += a2 * vf2;
              acc[h][3] += a2 * vf3;
            }
          }
        }
      }
      // fold the 2 edge-groups and write t-row to LDS
#pragma unroll
      for (int h = 0; h < H; ++h)
#pragma unroll
        for (int j = 0; j < 4; ++j) {
          acc[h][j].x += __shfl_xor(acc[h][j].x, 16);
          acc[h][j].y += __shfl_xor(acc[h][j].y, 16);
        }
      if (l < 16) {
#pragma unroll
        for (int h = 0; h < H; ++h) {
          uint4 pk;
          pk.x = (unsigned)f2b(acc[h][0].x) | ((unsigned)f2b(acc[h][0].y) << 16);
          pk.y = (unsigned)f2b(acc[h][1].x) | ((unsigned)f2b(acc[h][1].y) << 16);
          pk.z = (unsigned)f2b(acc[h][2].x) | ((unsigned)f2b(acc[h][2].y) << 16);
          pk.w = (unsigned)f2b(acc[h][3].x) | ((unsigned)f2b(acc[h][3].y) << 16);
          *(uint4*)&ts[slot][h * 128 + q * 8] = pk;
        }
      }
    }
  }
  __syncthreads();

  // ======== phase 2: post GEMM (8 waves, wave w -> col tile w) ========
  const int w = tid >> 6;
  const int lane = tid & 63;
  const int r = lane & 15, g = lane >> 4;
  const int koff = g << 3;
  f32x4 pacc = (f32x4)0.f;
#pragma unroll
  for (int kb = 0; kb < KD / 32; ++kb) {
    bf16x8 a = *(const bf16x8*)&ts[r][kb * 32 + koff];
    bf16x8 b = *(const bf16x8*)&Bp[((size_t)(kb * 8 + w) * 64 + lane) * 8];
    pacc = __builtin_amdgcn_mfma_f32_16x16x32_bf16(a, b, pacc, 0, 0, 0);
  }
  const int col = w * 16 + r;

  if constexpr (MODE == 0) {
    float ps[4][8];
#pragma unroll
    for (int i = 0; i < 4; ++i)
#pragma unroll
      for (int c = 0; c < 8; ++c) ps[i][c] = 0.f;
    float4 pj0 = *(const float4*)&Pf[col * 8];
    float4 pj1 = *(const float4*)&Pf[col * 8 + 4];
#pragma unroll
    for (int i = 0; i < 4; ++i) {
      const int row = n0 + g * 4 + i;
      float o = pacc[i];
      o = o > 0.f ? o : expm1f(o);
      houtf[(size_t)row * 128 + col] = o;
      houtb[(size_t)row * 128 + col] = f2b(o);
      ps[i][0] += o * pj0.x; ps[i][1] += o * pj0.y;
      ps[i][2] += o * pj0.z; ps[i][3] += o * pj0.w;
      ps[i][4] += o * pj1.x; ps[i][5] += o * pj1.y;
      ps[i][6] += o * pj1.z; ps[i][7] += o * pj1.w;
    }
#pragma unroll
    for (int off = 1; off < 16; off <<= 1)
#pragma unroll
      for (int i = 0; i < 4; ++i)
#pragma unroll
        for (int c = 0; c < 8; ++c) ps[i][c] += __shfl_xor(ps[i][c], off);
    if (r == 0) {
#pragma unroll
      for (int i = 0; i < 4; ++i)
#pragma unroll
        for (int c = 0; c < 8; ++c) s_pr[g * 4 + i][c][w] = ps[i][c];
    }
    __syncthreads();
    if (tid < 128) {
      int row = tid >> 3;
      int c = tid & 7;
      float val = 0.f;
#pragma unroll
      for (int ww = 0; ww < 8; ++ww) val += s_pr[row][c][ww];
      int gr = n0 + row;
      if (c < 4) eso[(size_t)gr * 4 + c] = val;
      else edo[(size_t)gr * 4 + (c - 4)] = val;
    }
  } else {
#pragma unroll
    for (int i = 0; i < 4; ++i) {
      float o = pacc[i];
      o = o > 0.f ? o : expm1f(o);
      xs[g * 4 + i][col] = f2b(o);
    }
    __syncthreads();
    f32x4 ai[3], ah[3];
#pragma unroll
    for (int p = 0; p < 3; ++p) {
      ai[p] = (f32x4)0.f;
      ah[p] = (f32x4)0.f;
    }
#pragma unroll
    for (int kb = 0; kb < 4; ++kb) {
      bf16x8 ax = *(const bf16x8*)&xs[r][kb * 32 + koff];
      bf16x8 ahr = *(const bf16x8*)&hbG[(size_t)(n0 + r) * 128 + kb * 32 + koff];
#pragma unroll
      for (int p = 0; p < 3; ++p) {
        const int ct = p * 8 + w;
        bf16x8 bi = *(const bf16x8*)&Bih[((size_t)(kb * 24 + ct) * 64 + lane) * 8];
        bf16x8 bh = *(const bf16x8*)&Bhh[((size_t)(kb * 24 + ct) * 64 + lane) * 8];
        ai[p] = __builtin_amdgcn_mfma_f32_16x16x32_bf16(ax, bi, ai[p], 0, 0, 0);
        ah[p] = __builtin_amdgcn_mfma_f32_16x16x32_bf16(ahr, bh, ah[p], 0, 0, 0);
      }
    }
    const int j = col;
    const float bir = bih[j], biz = bih[128 + j], bin = bih[256 + j];
    const float bhr = bhh[j], bhz = bhh[128 + j], bhn = bhh[256 + j];
    if constexpr (MODE == 1) {
      float ps[4][8];
#pragma unroll
      for (int i = 0; i < 4; ++i)
#pragma unroll
        for (int c = 0; c < 8; ++c) ps[i][c] = 0.f;
      float4 pj0 = *(const float4*)&Pf[j * 8];
      float4 pj1 = *(const float4*)&Pf[j * 8 + 4];
#pragma unroll
      for (int i = 0; i < 4; ++i) {
        const int row = n0 + g * 4 + i;
        float rr = sigmoidf_(ai[0][i] + bir + ah[0][i] + bhr);
        float z = sigmoidf_(ai[1][i] + biz + ah[1][i] + bhz);
        float nn = tanhf(ai[2][i] + bin + rr * (ah[2][i] + bhn));
        float hp = hf[(size_t)row * 128 + j];
        float o = (1.f - z) * nn + z * hp;
        houtf[(size_t)row * 128 + j] = o;
        houtb[(size_t)row * 128 + j] = f2b(o);
        ps[i][0] += o * pj0.x; ps[i][1] += o * pj0.y;
        ps[i][2] += o * pj0.z; ps[i][3] += o * pj0.w;
        ps[i][4] += o * pj1.x; ps[i][5] += o * pj1.y;
        ps[i][6] += o * pj1.z; ps[i][7] += o * pj1.w;
      }
#pragma unroll
      for (int off = 1; off < 16; off <<= 1)
#pragma unroll
        for (int i = 0; i < 4; ++i)
#pragma unroll
          for (int c = 0; c < 8; ++c) ps[i][c] += __shfl_xor(ps[i][c], off);
      if (r == 0) {
#pragma unroll
        for (int i = 0; i < 4; ++i)
#pragma unroll
          for (int c = 0; c < 8; ++c) s_pr[g * 4 + i][c][w] = ps[i][c];
      }
      __syncthreads();
      if (tid < 128) {
        int row = tid >> 3;
        int c = tid & 7;
        float val = 0.f;
#pragma unroll
        for (int ww = 0; ww < 8; ++ww) val += s_pr[row][c][ww];
        int gr = n0 + row;
        if (c < Hn) eso[(size_t)gr * Hn + c] = val;
        else if (c >= 4 && c < 4 + Hn) edo[(size_t)gr * Hn + (c - 4)] = val;
      }
    } else {
      // MODE == 2: fused sigmoid(h@W5 + b5) head
      float pfin[4] = {0.f, 0.f, 0.f, 0.f};
      const float w5 = W5[j];
#pragma unroll
      for (int i = 0; i < 4; ++i) {
        const int row = n0 + g * 4 + i;
        float rr = sigmoidf_(ai[0][i] + bir + ah[0][i] + bhr);
        float z = sigmoidf_(ai[1][i] + biz + ah[1][i] + bhz);
        float nn = tanhf(ai[2][i] + bin + rr * (ah[2][i] + bhn));
        float hp = hf[(size_t)row * 128 + j];
        float o = (1.f - z) * nn + z * hp;
        pfin[i] += o * w5;
      }
#pragma unroll
      for (int off = 1; off < 16; off <<= 1)
#pragma unroll
        for (int i = 0; i < 4; ++i) pfin[i] += __shfl_xor(pfin[i], off);
      if (r == 0) {
#pragma unroll
        for (int i = 0; i < 4; ++i) s_pr[g * 4 + i][0][w] = pfin[i];
      }
      __syncthreads();
      if (tid < 16) {
        float s = b5[0];
#pragma unroll
        for (int ww = 0; ww < 8; ++ww) s += s_pr[tid][0][ww];
        out[n0 + tid] = sigmoidf_(s);
      }
    }
  }
}

extern "C" void kernel_launch(void* const* d_in, const int* in_sizes, int n_in,
                              void* d_out, int out_size, void* d_ws, size_t ws_size,
                              hipStream_t stream) {
  const float* h0 = (const float*)d_in[0];
  const int* ei = (const int*)d_in[1];
  const float* W1 = (const float*)d_in[2];
  const float* as1 = (const float*)d_in[3];
  const float* ad1 = (const float*)d_in[4];
  const float* W2 = (const float*)d_in[5];
  const float* as2 = (const float*)d_in[6];
  const float* ad2 = (const float*)d_in[7];
  const float* W3 = (const float*)d_in[8];
  const float* as3 = (const float*)d_in[9];
  const float* ad3 = (const float*)d_in[10];
  const float* W4 = (const float*)d_in[11];
  const float* as4 = (const float*)d_in[12];
  const float* ad4 = (const float*)d_in[13];
  const float* Wih = (const float*)d_in[14];
  const float* Whh = (const float*)d_in[15];
  const float* bih = (const float*)d_in[16];
  const float* bhh = (const float*)d_in[17];
  const float* W5 = (const float*)d_in[18];
  const float* b5 = (const float*)d_in[19];

  const int N = in_sizes[0] / D;  // 20000
  const int E = in_sizes[1] / 2;  // 320000
  const int* src = ei;
  const int* dst = ei + E;

  // ---- workspace layout ----
  float* ws = (float*)d_ws;
  float* hA = ws;                                     // N*128 f32
  float* hB = hA + (size_t)N * 128;                   // N*128 f32
  float* esA = hB + (size_t)N * 128;                  // N*4
  float* edA = esA + (size_t)N * 4;                   // N*4
  float* esB = edA + (size_t)N * 4;                   // N*4
  float* edB = esB + (size_t)N * 4;                   // N*4
  unsigned short* h0b = (unsigned short*)(edB + (size_t)N * 4);  // N*128 us
  unsigned short* hAb = h0b + (size_t)N * 128;        // N*128 us
  unsigned short* hBb = hAb + (size_t)N * 128;        // N*128 us
  unsigned short* B1 = hBb + (size_t)N * 128;         // 65536 us
  unsigned short* B2 = B1 + 65536;                    // 65536 us
  unsigned short* B3 = B2 + 65536;                    // 65536 us
  unsigned short* B4 = B3 + 65536;                    // 16384 us
  unsigned short* Bih = B4 + 16384;                   // 49152 us
  unsigned short* Bhh = Bih + 49152;                  // 49152 us
  unsigned short* Pp1 = Bhh + 49152;                  // 2048 us
  float* Pf2 = (float*)(Pp1 + 2048);                  // 1024 f
  float* Pf3 = Pf2 + 1024;                            // 1024 f
  float* Pf4 = Pf3 + 1024;                            // 1024 f
  int* deg = (int*)(Pf4 + 1024);                      // N
  int* rowptr = deg + N;                              // N+1
  int* fill = rowptr + N + 1;                         // N
  int* srcs = fill + N;                               // E

  // ---- prep ----
  hipMemsetAsync(deg, 0, (size_t)N * 4, stream);
  {
    const int total = N * 128 + 311296 + 2048 + 3072 + E;
    k_prep<<<(total + 255) / 256, 256, 0, stream>>>(
        h0, h0b, W1, W2, W3, W4, Wih, Whh, B1, B2, B3, B4, Bih, Bhh,
        as1, ad1, as2, ad2, as3, ad3, as4, ad4, Pp1, Pf2, Pf3, Pf4, dst, deg, N, E);
  }
  k_scan<<<1, 1024, 0, stream>>>(deg, rowptr, fill, N);
  {
    const int nS = (E + 255) / 256;
    const int nE = (N + 63) / 64;
    k_scatter_esed<<<nS + nE, 256, 0, stream>>>(src, dst, fill, srcs, E,
                                                h0b, Pp1, esA, edA, N, nS);
  }

  const int gL = N / 16;  // 1250

  // ---- layer 1: H=4, no GRU; emits h1 (hA/hAb) + es/ed(L2) -> B buffers ----
  k_layer<4, 0><<<gL, 512, 0, stream>>>(rowptr, srcs, esA, edA, h0b, B1,
                                        nullptr, nullptr, nullptr, nullptr, nullptr,
                                        hA, hAb, Pf2, esB, edB, 4, nullptr, nullptr, nullptr);
  // ---- layer 2: H=4, GRU; emits h2 (hB/hBb) + es/ed(L3) -> A buffers ----
  k_layer<4, 1><<<gL, 512, 0, stream>>>(rowptr, srcs, esB, edB, hAb, B2,
                                        hA, Bih, Bhh, bih, bhh,
                                        hB, hBb, Pf3, esA, edA, 4, nullptr, nullptr, nullptr);
  // ---- layer 3: H=4, GRU; emits h3 (hA/hAb) + es/ed(L4, Hn=1) -> B buffers ----
  k_layer<4, 1><<<gL, 512, 0, stream>>>(rowptr, srcs, esA, edA, hBb, B3,
                                        hB, Bih, Bhh, bih, bhh,
                                        hA, hAb, Pf4, esB, edB, 1, nullptr, nullptr, nullptr);
  // ---- layer 4: H=1, GRU + fused output head ----
  k_layer<1, 2><<<gL, 512, 0, stream>>>(rowptr, srcs, esB, edB, hAb, B4,
                                        hA, Bih, Bhh, bih, bhh,
                                        nullptr, nullptr, nullptr, nullptr, nullptr, 0,
                                        W5, b5, (float*)d_out);
}